// Round 20
// baseline (69.555 us; speedup 1.0000x reference)
//
#include <hip/hip_runtime.h>
#include <stdint.h>

// Problem: x (4096,2048) int32 {0,1}; references (1024,2048) f32 {0,1};
// out (4096,1024) f32 = (hamming - 1024) / (0.5*sqrt(2048)).
// Identity: s=1-2x, t=1-2r in {+-1}: hamming = (2048 - s.t)/2 ->
//   out[b,d] = -(inv_std/2) * dot_pm1(b,d)     (exact integer dot)
// fp4 E2M1: +1=0x2, -1=0xA; MX scales all 1.0 (E8M0 0x7F) -> exact f32 dot.
//
// DIAGNOSTIC ROUND 3 (fixed): R19's REPS wrapper raced because the per-rep
// epilogue's global STORES increment vmcnt, corrupting the loop's counted
// s_waitcnt vmcnt(3) in reps>=2. Fix: full vmcnt(0) drain + barrier at each
// rep boundary -> every rep starts with 0 outstanding vm-ops (the invariant
// the R12 schedule was verified under). REPS=8 puts the GEMM dispatch
// (~8x its true cost) above the ~40us ws-poison fills -> visible counters.
constexpr int B_ROWS = 4096;
constexpr int D_ROWS = 1024;
constexpr int L_LEN  = 2048;
constexpr int LB     = L_LEN / 2;        // 1024 B per row at fp4
constexpr int GEMM_REPS = 8;

using int32x4 = __attribute__((ext_vector_type(4))) int;
using int32x8 = __attribute__((ext_vector_type(8))) int;
using f32x16  = __attribute__((ext_vector_type(16))) float;

// ---------------------------------------------------------------------------
// Kernel 1 (R15 VERBATIM — control): coalesced wave-segment fp4 convert.
// ---------------------------------------------------------------------------
constexpr int XSEGS = B_ROWS * 4;              // 16384 x-segments (512 elems)
constexpr int RSEGS = D_ROWS * 4;              //  4096 r-segments
constexpr int CVT_BLOCKS = (XSEGS + RSEGS) / 4;  // 5120 blocks of 4 waves

__global__ __launch_bounds__(256) void convert_fp4_kernel(
    const int* __restrict__ x, const float* __restrict__ r,
    uint32_t* __restrict__ xq, uint32_t* __restrict__ rq)
{
  const int wave = (int)((blockIdx.x * blockDim.x + threadIdx.x) >> 6);
  const int lane = threadIdx.x & 63;
  uint32_t wo;
  if (wave < XSEGS) {                        // wave-uniform branch
    const int row = wave >> 2, seg = wave & 3;
    const int* s = x + (size_t)row * L_LEN + seg * 512 + lane * 4;
    const int4 v0 = *reinterpret_cast<const int4*>(s);
    const int4 v1 = *reinterpret_cast<const int4*>(s + 256);
    wo  = (v0.x ? 0xAu : 0x2u);
    wo |= (v0.y ? 0xAu : 0x2u) << 4;
    wo |= (v0.z ? 0xAu : 0x2u) << 8;
    wo |= (v0.w ? 0xAu : 0x2u) << 12;
    wo |= (v1.x ? 0xAu : 0x2u) << 16;
    wo |= (v1.y ? 0xAu : 0x2u) << 20;
    wo |= (v1.z ? 0xAu : 0x2u) << 24;
    wo |= (v1.w ? 0xAu : 0x2u) << 28;
    xq[row * 256 + seg * 64 + lane] = wo;
  } else {
    const int sr  = wave - XSEGS;
    const int row = sr >> 2, seg = sr & 3;
    const float* s = r + (size_t)row * L_LEN + seg * 512 + lane * 4;
    const float4 v0 = *reinterpret_cast<const float4*>(s);
    const float4 v1 = *reinterpret_cast<const float4*>(s + 256);
    wo  = (v0.x != 0.0f ? 0xAu : 0x2u);
    wo |= (v0.y != 0.0f ? 0xAu : 0x2u) << 4;
    wo |= (v0.z != 0.0f ? 0xAu : 0x2u) << 8;
    wo |= (v0.w != 0.0f ? 0xAu : 0x2u) << 12;
    wo |= (v1.x != 0.0f ? 0xAu : 0x2u) << 16;
    wo |= (v1.y != 0.0f ? 0xAu : 0x2u) << 20;
    wo |= (v1.z != 0.0f ? 0xAu : 0x2u) << 24;
    wo |= (v1.w != 0.0f ? 0xAu : 0x2u) << 28;
    rq[row * 256 + seg * 64 + lane] = wo;
  }
}

// ---------------------------------------------------------------------------
// Kernel 2: R12's MX-fp4 GEMM, whole body x GEMM_REPS with per-rep vmcnt(0)
// drain (store-safe rep boundaries).
// ---------------------------------------------------------------------------
constexpr int BM = 128;
constexpr int BN = 64;
constexpr int BKB = 64;                  // K-step bytes per row (128 elems)
constexpr int KSTEPS = LB / BKB;         // 16
constexpr int GRID_D = D_ROWS / BN;      // 16
constexpr int NWG = (B_ROWS / BM) * GRID_D;   // 512

typedef __attribute__((address_space(3))) void       as3_void;
typedef const __attribute__((address_space(1))) void as1_cvoid;

__device__ __forceinline__ void gload_lds16(const void* g, void* l) {
  __builtin_amdgcn_global_load_lds((as1_cvoid*)g, (as3_void*)l, 16, 0, 0);
}

__global__ __launch_bounds__(256) void gemm_fp4_kernel(
    const uint8_t* __restrict__ Aq, const uint8_t* __restrict__ Bq,
    float* __restrict__ out)
{
  __shared__ __align__(16) uint8_t A_lds[3][BM * BKB];   // 3 x 8 KB
  __shared__ __align__(16) uint8_t B_lds[3][BN * BKB];   // 3 x 4 KB

  const int lin = blockIdx.x;
  const int swz = (lin & 7) * (NWG / 8) + (lin >> 3);   // bijective, 512%8==0
  const int bm  = (swz / GRID_D) * BM;
  const int bn  = (swz % GRID_D) * BN;

  const int t    = threadIdx.x;
  const int lane = t & 63;
  const int w    = t >> 6;          // wave 0..3
  const int wr   = w >> 1;          // wave row (m): tile rows wr*64..+64
  const int wc   = w & 1;           // wave col (n): tile cols wc*32..+32

  const uint8_t* gA[2];
#pragma unroll
  for (int c = 0; c < 2; ++c) {
    const int rr = w * 32 + c * 16 + (lane >> 2);
    gA[c] = Aq + (size_t)(bm + rr) * LB + (((lane & 3) ^ ((rr >> 1) & 3)) * 16);
  }
  const int rB = w * 16 + (lane >> 2);
  const uint8_t* gB0 =
      Bq + (size_t)(bn + rB) * LB + (((lane & 3) ^ ((rB >> 1) & 3)) * 16);

#define STAGE(buf, k0b) do {                                                  \
    _Pragma("unroll") for (int _c = 0; _c < 2; ++_c)                          \
      gload_lds16(gA[_c] + (k0b), A_lds[buf] + (w * 32 + _c * 16) * BKB);     \
    gload_lds16(gB0 + (k0b), B_lds[buf] + (w * 16) * BKB);                    \
  } while (0)

#define COMPUTE(cur) do {                                                     \
    _Pragma("unroll") for (int kc = 0; kc < 2; ++kc) {                        \
      const int rowB = wc * 32 + (lane & 31);                                 \
      const int qB   = 2 * kc + (lane >> 5);                                  \
      const int32x4 b4 = *reinterpret_cast<const int32x4*>(                   \
          B_lds[cur] + rowB * BKB + ((qB ^ ((rowB >> 1) & 3)) * 16));         \
      const int32x8 b8 = {b4[0], b4[1], b4[2], b4[3], 0, 0, 0, 0};            \
      _Pragma("unroll") for (int f = 0; f < 2; ++f) {                         \
        const int rowA = wr * 64 + f * 32 + (lane & 31);                      \
        const int qA   = 2 * kc + (lane >> 5);                                \
        const int32x4 a4 = *reinterpret_cast<const int32x4*>(                 \
            A_lds[cur] + rowA * BKB + ((qA ^ ((rowA >> 1) & 3)) * 16));       \
        const int32x8 a8 = {a4[0], a4[1], a4[2], a4[3], 0, 0, 0, 0};          \
        acc[f] = __builtin_amdgcn_mfma_scale_f32_32x32x64_f8f6f4(             \
            a8, b8, acc[f], 4, 4, 0, 0x7F7F7F7F, 0, 0x7F7F7F7F);              \
      }                                                                       \
    } } while (0)

  const float scale = -0.5f * 0.04419417382415922f;
  const int col = bn + wc * 32 + (lane & 31);

  for (int rep = 0; rep < GEMM_REPS; ++rep) {
    asm volatile("" ::: "memory");   // keep reps distinct (no cross-rep CSE)

    f32x16 acc[2] = {};

    STAGE(0, 0);
    STAGE(1, BKB);                    // 6 loads in flight (and ONLY 6:
                                      // rep starts with vmcnt empty)

#pragma unroll 3
    for (int ks = 0; ks < KSTEPS - 1; ++ks) {   // 15 iters; cur static
      const int cur = ks % 3;
      asm volatile("s_waitcnt vmcnt(3)" ::: "memory");  // tile ks landed
      __builtin_amdgcn_sched_barrier(0);                // rule #18
      __builtin_amdgcn_s_barrier();                     // raw barrier
      if (ks + 2 < KSTEPS) STAGE((ks + 2) % 3, (ks + 2) * BKB);
      COMPUTE(cur);
    }
    asm volatile("s_waitcnt vmcnt(0)" ::: "memory");
    __builtin_amdgcn_sched_barrier(0);
    __builtin_amdgcn_s_barrier();
    COMPUTE(0);

    // Epilogue (identical values every rep -> idempotent).
#pragma unroll
    for (int f = 0; f < 2; ++f) {
#pragma unroll
      for (int reg = 0; reg < 16; ++reg) {
        const int row = bm + wr * 64 + f * 32 + (reg & 3) + 8 * (reg >> 2)
                      + 4 * (lane >> 5);
        out[(size_t)row * D_ROWS + col] = acc[f][reg] * scale;
      }
    }

    // REP BOUNDARY FIX: drain ALL vm ops (incl. the epilogue stores that
    // would otherwise pollute the next rep's counted vmcnt), then barrier
    // so no wave re-stages buf 0/1 while others still read them.
    asm volatile("s_waitcnt vmcnt(0)" ::: "memory");
    __builtin_amdgcn_sched_barrier(0);
    __builtin_amdgcn_s_barrier();
  }
#undef STAGE
#undef COMPUTE
}

extern "C" void kernel_launch(void* const* d_in, const int* in_sizes, int n_in,
                              void* d_out, int out_size, void* d_ws, size_t ws_size,
                              hipStream_t stream) {
  const int*   x = (const int*)d_in[0];     // (4096, 2048) int32
  const float* r = (const float*)d_in[1];   // (1024, 2048) float32
  float*     out = (float*)d_out;           // (4096, 1024) float32

  uint8_t* Aq = (uint8_t*)d_ws;                         // 4 MiB (4096x1024 B)
  uint8_t* Bq = Aq + (size_t)B_ROWS * LB;               // 1 MiB (1024x1024 B)

  convert_fp4_kernel<<<CVT_BLOCKS, 256, 0, stream>>>(
      x, r, (uint32_t*)Aq, (uint32_t*)Bq);

  gemm_fp4_kernel<<<NWG, 256, 0, stream>>>(Aq, Bq, out);  // 512 blocks
}

// Round 22
// 33.269 us; speedup vs baseline: 2.0906x; 2.0906x over previous
//
#include <hip/hip_runtime.h>
#include <stdint.h>

// Problem: x (4096,2048) int32 {0,1}; references (1024,2048) f32 {0,1};
// out (4096,1024) f32 = (hamming - 1024) / (0.5*sqrt(2048)).
// Identity: s=1-2x, t=1-2r in {+-1}: hamming = (2048 - s.t)/2 ->
//   out[b,d] = -(inv_std/2) * dot_pm1(b,d)     (exact integer dot)
// fp4 E2M1: +1=0x2, -1=0xA; MX scales all 1.0 (E8M0 0x7F) -> exact f32 dot.
//
// R20 ledger: convert+gap ~2.7us, GEMM warm 6.36us, GEMM pass-1 22.3us.
// Theory: pass-1 reads operand lines left DIRTY in REMOTE XCD L2s by the
// convert (round-robin block placement) -> cross-XCD dirty resolution.
// R21's NT-store fix broke inter-kernel visibility (tripwire) — reverted.
// THIS ROUND: make every producer line XCD-LOCAL to its consumer using the
// blockIdx%8->XCD round-robin heuristic (T1's basis):
//   A: convert block b writes row (b&7)*512 + (b>>3)  -> writer XCD b&7 ==
//      reader XCD (GEMM block lin&7 reads A rows [(lin&7)*512, +512)).
//   B: replicated x8 (8 MB of the 256 MB ws); copy j written by blocks with
//      b&7==j, read by GEMM blocks with lin&7==j. All dirty lines local.
constexpr int B_ROWS = 4096;
constexpr int D_ROWS = 1024;
constexpr int L_LEN  = 2048;
constexpr int LB     = L_LEN / 2;        // 1024 B per row at fp4

using int32x4 = __attribute__((ext_vector_type(4))) int;
using int32x8 = __attribute__((ext_vector_type(8))) int;
using f32x16  = __attribute__((ext_vector_type(16))) float;

// ---------------------------------------------------------------------------
// Kernel 1: coalesced wave-segment fp4 convert (R15 access pattern), with
// XCD-aligned block->row remap and 8x B replication. Plain coherent stores.
// Block b (256 thr = 4 waves = 4 segments = one full row):
//   b < 4096:           A row (b&7)*512 + (b>>3)
//   b in [4096, 12288): B copy (b&7), row (b-4096)>>3   [4096%8==0]
// ---------------------------------------------------------------------------
constexpr int CVT_BLOCKS = B_ROWS + 8 * D_ROWS;   // 12288
constexpr int BCOPY_DW   = D_ROWS * 256;          // dwords per B copy (1 MiB)

__global__ __launch_bounds__(256) void convert_fp4_kernel(
    const int* __restrict__ x, const float* __restrict__ r,
    uint32_t* __restrict__ xq, uint32_t* __restrict__ rq)
{
  const int b    = blockIdx.x;
  const int seg  = threadIdx.x >> 6;   // wave 0..3 = segment
  const int lane = threadIdx.x & 63;
  uint32_t wo;
  if (b < B_ROWS) {
    const int row = (b & 7) * 512 + (b >> 3);      // writer XCD == reader XCD
    const int* s = x + (size_t)row * L_LEN + seg * 512 + lane * 4;
    const int4 v0 = *reinterpret_cast<const int4*>(s);
    const int4 v1 = *reinterpret_cast<const int4*>(s + 256);
    wo  = (v0.x ? 0xAu : 0x2u);
    wo |= (v0.y ? 0xAu : 0x2u) << 4;
    wo |= (v0.z ? 0xAu : 0x2u) << 8;
    wo |= (v0.w ? 0xAu : 0x2u) << 12;
    wo |= (v1.x ? 0xAu : 0x2u) << 16;
    wo |= (v1.y ? 0xAu : 0x2u) << 20;
    wo |= (v1.z ? 0xAu : 0x2u) << 24;
    wo |= (v1.w ? 0xAu : 0x2u) << 28;
    xq[row * 256 + seg * 64 + lane] = wo;
  } else {
    const int c    = b - B_ROWS;
    const int copy = c & 7;                        // == writer XCD (heuristic)
    const int row  = c >> 3;
    const float* s = r + (size_t)row * L_LEN + seg * 512 + lane * 4;
    const float4 v0 = *reinterpret_cast<const float4*>(s);
    const float4 v1 = *reinterpret_cast<const float4*>(s + 256);
    wo  = (v0.x != 0.0f ? 0xAu : 0x2u);
    wo |= (v0.y != 0.0f ? 0xAu : 0x2u) << 4;
    wo |= (v0.z != 0.0f ? 0xAu : 0x2u) << 8;
    wo |= (v0.w != 0.0f ? 0xAu : 0x2u) << 12;
    wo |= (v1.x != 0.0f ? 0xAu : 0x2u) << 16;
    wo |= (v1.y != 0.0f ? 0xAu : 0x2u) << 20;
    wo |= (v1.z != 0.0f ? 0xAu : 0x2u) << 24;
    wo |= (v1.w != 0.0f ? 0xAu : 0x2u) << 28;
    rq[(size_t)copy * BCOPY_DW + row * 256 + seg * 64 + lane] = wo;
  }
}

// ---------------------------------------------------------------------------
// Kernel 2 (R12 structure; ONLY change: B base -> this XCD's local copy):
// MX-fp4 GEMM, 3-buffer counted-vmcnt pipeline (warm marginal 6.36us).
// ---------------------------------------------------------------------------
constexpr int BM = 128;
constexpr int BN = 64;
constexpr int BKB = 64;                  // K-step bytes per row (128 elems)
constexpr int KSTEPS = LB / BKB;         // 16
constexpr int GRID_D = D_ROWS / BN;      // 16
constexpr int NWG = (B_ROWS / BM) * GRID_D;   // 512

typedef __attribute__((address_space(3))) void       as3_void;
typedef const __attribute__((address_space(1))) void as1_cvoid;

__device__ __forceinline__ void gload_lds16(const void* g, void* l) {
  __builtin_amdgcn_global_load_lds((as1_cvoid*)g, (as3_void*)l, 16, 0, 0);
}

__global__ __launch_bounds__(256) void gemm_fp4_kernel(
    const uint8_t* __restrict__ Aq, const uint8_t* __restrict__ Bq_all,
    float* __restrict__ out)
{
  __shared__ __align__(16) uint8_t A_lds[3][BM * BKB];   // 3 x 8 KB
  __shared__ __align__(16) uint8_t B_lds[3][BN * BKB];   // 3 x 4 KB

  const int lin = blockIdx.x;
  const int swz = (lin & 7) * (NWG / 8) + (lin >> 3);   // bijective, 512%8==0
  const int bm  = (swz / GRID_D) * BM;
  const int bn  = (swz % GRID_D) * BN;

  // This XCD's local B copy (written by convert blocks with the same &7).
  const uint8_t* __restrict__ Bq =
      Bq_all + (size_t)(lin & 7) * (D_ROWS * (size_t)LB);

  const int t    = threadIdx.x;
  const int lane = t & 63;
  const int w    = t >> 6;          // wave 0..3
  const int wr   = w >> 1;          // wave row (m): tile rows wr*64..+64
  const int wc   = w & 1;           // wave col (n): tile cols wc*32..+32

  const uint8_t* gA[2];
#pragma unroll
  for (int c = 0; c < 2; ++c) {
    const int rr = w * 32 + c * 16 + (lane >> 2);
    gA[c] = Aq + (size_t)(bm + rr) * LB + (((lane & 3) ^ ((rr >> 1) & 3)) * 16);
  }
  const int rB = w * 16 + (lane >> 2);
  const uint8_t* gB0 =
      Bq + (size_t)(bn + rB) * LB + (((lane & 3) ^ ((rB >> 1) & 3)) * 16);

#define STAGE(buf, k0b) do {                                                  \
    _Pragma("unroll") for (int _c = 0; _c < 2; ++_c)                          \
      gload_lds16(gA[_c] + (k0b), A_lds[buf] + (w * 32 + _c * 16) * BKB);     \
    gload_lds16(gB0 + (k0b), B_lds[buf] + (w * 16) * BKB);                    \
  } while (0)

#define COMPUTE(cur) do {                                                     \
    _Pragma("unroll") for (int kc = 0; kc < 2; ++kc) {                        \
      const int rowB = wc * 32 + (lane & 31);                                 \
      const int qB   = 2 * kc + (lane >> 5);                                  \
      const int32x4 b4 = *reinterpret_cast<const int32x4*>(                   \
          B_lds[cur] + rowB * BKB + ((qB ^ ((rowB >> 1) & 3)) * 16));         \
      const int32x8 b8 = {b4[0], b4[1], b4[2], b4[3], 0, 0, 0, 0};            \
      _Pragma("unroll") for (int f = 0; f < 2; ++f) {                         \
        const int rowA = wr * 64 + f * 32 + (lane & 31);                      \
        const int qA   = 2 * kc + (lane >> 5);                                \
        const int32x4 a4 = *reinterpret_cast<const int32x4*>(                 \
            A_lds[cur] + rowA * BKB + ((qA ^ ((rowA >> 1) & 3)) * 16));       \
        const int32x8 a8 = {a4[0], a4[1], a4[2], a4[3], 0, 0, 0, 0};          \
        acc[f] = __builtin_amdgcn_mfma_scale_f32_32x32x64_f8f6f4(             \
            a8, b8, acc[f], 4, 4, 0, 0x7F7F7F7F, 0, 0x7F7F7F7F);              \
      }                                                                       \
    } } while (0)

  f32x16 acc[2] = {};

  STAGE(0, 0);
  STAGE(1, BKB);                    // 6 loads in flight

#pragma unroll 3
  for (int ks = 0; ks < KSTEPS - 1; ++ks) {   // 15 iters, cur/(ks+2)%3 static
    const int cur = ks % 3;
    asm volatile("s_waitcnt vmcnt(3)" ::: "memory");  // tile ks landed
    __builtin_amdgcn_sched_barrier(0);                // rule #18
    __builtin_amdgcn_s_barrier();                     // raw: no vmcnt(0) drain
    if (ks + 2 < KSTEPS) STAGE((ks + 2) % 3, (ks + 2) * BKB);
    COMPUTE(cur);
  }
  asm volatile("s_waitcnt vmcnt(0)" ::: "memory");
  __builtin_amdgcn_sched_barrier(0);
  __builtin_amdgcn_s_barrier();
  COMPUTE(0);

#undef STAGE
#undef COMPUTE

  // Epilogue: verified 32x32 C/D layout: col = lane&31,
  // row = (reg&3) + 8*(reg>>2) + 4*(lane>>5).
  const float scale = -0.5f * 0.04419417382415922f;
  const int col = bn + wc * 32 + (lane & 31);
#pragma unroll
  for (int f = 0; f < 2; ++f) {
#pragma unroll
    for (int reg = 0; reg < 16; ++reg) {
      const int row = bm + wr * 64 + f * 32 + (reg & 3) + 8 * (reg >> 2)
                    + 4 * (lane >> 5);
      out[(size_t)row * D_ROWS + col] = acc[f][reg] * scale;
    }
  }
}

extern "C" void kernel_launch(void* const* d_in, const int* in_sizes, int n_in,
                              void* d_out, int out_size, void* d_ws, size_t ws_size,
                              hipStream_t stream) {
  const int*   x = (const int*)d_in[0];     // (4096, 2048) int32
  const float* r = (const float*)d_in[1];   // (1024, 2048) float32
  float*     out = (float*)d_out;           // (4096, 1024) float32

  uint8_t* Aq = (uint8_t*)d_ws;                         // 4 MiB fp4 A
  uint8_t* Bq = Aq + (size_t)B_ROWS * LB;               // 8 x 1 MiB B copies

  convert_fp4_kernel<<<CVT_BLOCKS, 256, 0, stream>>>(
      x, r, (uint32_t*)Aq, (uint32_t*)Bq);

  gemm_fp4_kernel<<<NWG, 256, 0, stream>>>(Aq, Bq, out);  // 512 blocks
}

// Round 23
// 25.668 us; speedup vs baseline: 2.7098x; 1.2961x over previous
//
#include <hip/hip_runtime.h>
#include <stdint.h>

// Problem: x (4096,2048) int32 {0,1}; references (1024,2048) f32 {0,1};
// out (4096,1024) f32 = (hamming - 1024) / (0.5*sqrt(2048)).
// Identity: s=1-2x, t=1-2r in {+-1}: hamming = (2048 - s.t)/2 ->
//   out[b,d] = -(inv_std/2) * dot_pm1(b,d)     (exact integer dot)
// fp4 E2M1: +1=0x2, -1=0xA; MX scales all 1.0 (E8M0 0x7F) -> exact f32 dot.
//
// Ledger (REPS-calibrated): convert warm 1.24us | GEMM warm 6.36us |
// GEMM as-dispatched ~22us. The ~16us delta: pass-1 streams operands from
// L3/HBM after the dispatch-boundary L2 invalidate, and R12's pipeline has
// only 2 tiles (~800ns) of lookahead -> every K-step stalls on cold latency.
// (Cross-XCD-dirty theory REFUTED by R21/R22.) THIS ROUND: depth 2 -> 4
// (NBUF=5, vmcnt(9), 60 KB LDS) so ~1.4us of latency is covered in-flight.
constexpr int B_ROWS = 4096;
constexpr int D_ROWS = 1024;
constexpr int L_LEN  = 2048;
constexpr int LB     = L_LEN / 2;        // 1024 B per row at fp4

using int32x4 = __attribute__((ext_vector_type(4))) int;
using int32x8 = __attribute__((ext_vector_type(8))) int;
using f32x16  = __attribute__((ext_vector_type(16))) float;

// ---------------------------------------------------------------------------
// Kernel 1 (R15 VERBATIM — control, C_warm=1.24us): coalesced wave-segment
// fp4 convert.
// ---------------------------------------------------------------------------
constexpr int XSEGS = B_ROWS * 4;              // 16384 x-segments (512 elems)
constexpr int RSEGS = D_ROWS * 4;              //  4096 r-segments
constexpr int CVT_BLOCKS = (XSEGS + RSEGS) / 4;  // 5120 blocks of 4 waves

__global__ __launch_bounds__(256) void convert_fp4_kernel(
    const int* __restrict__ x, const float* __restrict__ r,
    uint32_t* __restrict__ xq, uint32_t* __restrict__ rq)
{
  const int wave = (int)((blockIdx.x * blockDim.x + threadIdx.x) >> 6);
  const int lane = threadIdx.x & 63;
  uint32_t wo;
  if (wave < XSEGS) {                        // wave-uniform branch
    const int row = wave >> 2, seg = wave & 3;
    const int* s = x + (size_t)row * L_LEN + seg * 512 + lane * 4;
    const int4 v0 = *reinterpret_cast<const int4*>(s);
    const int4 v1 = *reinterpret_cast<const int4*>(s + 256);
    wo  = (v0.x ? 0xAu : 0x2u);
    wo |= (v0.y ? 0xAu : 0x2u) << 4;
    wo |= (v0.z ? 0xAu : 0x2u) << 8;
    wo |= (v0.w ? 0xAu : 0x2u) << 12;
    wo |= (v1.x ? 0xAu : 0x2u) << 16;
    wo |= (v1.y ? 0xAu : 0x2u) << 20;
    wo |= (v1.z ? 0xAu : 0x2u) << 24;
    wo |= (v1.w ? 0xAu : 0x2u) << 28;
    xq[row * 256 + seg * 64 + lane] = wo;
  } else {
    const int sr  = wave - XSEGS;
    const int row = sr >> 2, seg = sr & 3;
    const float* s = r + (size_t)row * L_LEN + seg * 512 + lane * 4;
    const float4 v0 = *reinterpret_cast<const float4*>(s);
    const float4 v1 = *reinterpret_cast<const float4*>(s + 256);
    wo  = (v0.x != 0.0f ? 0xAu : 0x2u);
    wo |= (v0.y != 0.0f ? 0xAu : 0x2u) << 4;
    wo |= (v0.z != 0.0f ? 0xAu : 0x2u) << 8;
    wo |= (v0.w != 0.0f ? 0xAu : 0x2u) << 12;
    wo |= (v1.x != 0.0f ? 0xAu : 0x2u) << 16;
    wo |= (v1.y != 0.0f ? 0xAu : 0x2u) << 20;
    wo |= (v1.z != 0.0f ? 0xAu : 0x2u) << 24;
    wo |= (v1.w != 0.0f ? 0xAu : 0x2u) << 28;
    rq[row * 256 + seg * 64 + lane] = wo;
  }
}

// ---------------------------------------------------------------------------
// Kernel 2: MX-fp4 GEMM, DEPTH-4 counted-vmcnt pipeline (R12 geometry).
// NBUF=5 x 12 KB = 60 KB LDS; prologue stages tiles 0-3 (12 loads); step ks:
// wait vmcnt(9/6/3/0 per tail), barrier, stage tile ks+4 into buf (ks+4)%5
// (read last at step ks-1, barrier-protected), compute buf ks%5.
// ---------------------------------------------------------------------------
constexpr int BM = 128;
constexpr int BN = 64;
constexpr int BKB = 64;                  // K-step bytes per row (128 elems)
constexpr int KSTEPS = LB / BKB;         // 16
constexpr int NBUF = 5;
constexpr int GRID_D = D_ROWS / BN;      // 16
constexpr int NWG = (B_ROWS / BM) * GRID_D;   // 512

typedef __attribute__((address_space(3))) void       as3_void;
typedef const __attribute__((address_space(1))) void as1_cvoid;

__device__ __forceinline__ void gload_lds16(const void* g, void* l) {
  __builtin_amdgcn_global_load_lds((as1_cvoid*)g, (as3_void*)l, 16, 0, 0);
}

__global__ __launch_bounds__(256) void gemm_fp4_kernel(
    const uint8_t* __restrict__ Aq, const uint8_t* __restrict__ Bq,
    float* __restrict__ out)
{
  __shared__ __align__(16) uint8_t A_lds[NBUF][BM * BKB];   // 5 x 8 KB
  __shared__ __align__(16) uint8_t B_lds[NBUF][BN * BKB];   // 5 x 4 KB

  const int lin = blockIdx.x;
  const int swz = (lin & 7) * (NWG / 8) + (lin >> 3);   // bijective, 512%8==0
  const int bm  = (swz / GRID_D) * BM;
  const int bn  = (swz % GRID_D) * BN;

  const int t    = threadIdx.x;
  const int lane = t & 63;
  const int w    = t >> 6;          // wave 0..3
  const int wr   = w >> 1;          // wave row (m): tile rows wr*64..+64
  const int wc   = w & 1;           // wave col (n): tile cols wc*32..+32

  const uint8_t* gA[2];
#pragma unroll
  for (int c = 0; c < 2; ++c) {
    const int rr = w * 32 + c * 16 + (lane >> 2);
    gA[c] = Aq + (size_t)(bm + rr) * LB + (((lane & 3) ^ ((rr >> 1) & 3)) * 16);
  }
  const int rB = w * 16 + (lane >> 2);
  const uint8_t* gB0 =
      Bq + (size_t)(bn + rB) * LB + (((lane & 3) ^ ((rB >> 1) & 3)) * 16);

#define STAGE(buf, k0b) do {                                                  \
    _Pragma("unroll") for (int _c = 0; _c < 2; ++_c)                          \
      gload_lds16(gA[_c] + (k0b), A_lds[buf] + (w * 32 + _c * 16) * BKB);     \
    gload_lds16(gB0 + (k0b), B_lds[buf] + (w * 16) * BKB);                    \
  } while (0)

#define COMPUTE(cur) do {                                                     \
    _Pragma("unroll") for (int kc = 0; kc < 2; ++kc) {                        \
      const int rowB = wc * 32 + (lane & 31);                                 \
      const int qB   = 2 * kc + (lane >> 5);                                  \
      const int32x4 b4 = *reinterpret_cast<const int32x4*>(                   \
          B_lds[cur] + rowB * BKB + ((qB ^ ((rowB >> 1) & 3)) * 16));         \
      const int32x8 b8 = {b4[0], b4[1], b4[2], b4[3], 0, 0, 0, 0};            \
      _Pragma("unroll") for (int f = 0; f < 2; ++f) {                         \
        const int rowA = wr * 64 + f * 32 + (lane & 31);                      \
        const int qA   = 2 * kc + (lane >> 5);                                \
        const int32x4 a4 = *reinterpret_cast<const int32x4*>(                 \
            A_lds[cur] + rowA * BKB + ((qA ^ ((rowA >> 1) & 3)) * 16));       \
        const int32x8 a8 = {a4[0], a4[1], a4[2], a4[3], 0, 0, 0, 0};          \
        acc[f] = __builtin_amdgcn_mfma_scale_f32_32x32x64_f8f6f4(             \
            a8, b8, acc[f], 4, 4, 0, 0x7F7F7F7F, 0, 0x7F7F7F7F);              \
      }                                                                       \
    } } while (0)

  f32x16 acc[2] = {};

  STAGE(0, 0);
  STAGE(1, 1 * BKB);
  STAGE(2, 2 * BKB);
  STAGE(3, 3 * BKB);                // 12 loads (4 tiles) in flight

#pragma unroll
  for (int ks = 0; ks < KSTEPS; ++ks) {        // fully unrolled: all static
    const int rem = KSTEPS - 1 - ks;           // tiles still outstanding
    // Wait until own tile ks landed: allowed outstanding = 3*min(rem,3).
    if (rem >= 3)      asm volatile("s_waitcnt vmcnt(9)" ::: "memory");
    else if (rem == 2) asm volatile("s_waitcnt vmcnt(6)" ::: "memory");
    else if (rem == 1) asm volatile("s_waitcnt vmcnt(3)" ::: "memory");
    else               asm volatile("s_waitcnt vmcnt(0)" ::: "memory");
    __builtin_amdgcn_sched_barrier(0);         // rule #18
    __builtin_amdgcn_s_barrier();              // raw: no full drain
    if (ks + 4 < KSTEPS) STAGE((ks + 4) % NBUF, (ks + 4) * BKB);
    COMPUTE(ks % NBUF);
  }
#undef STAGE
#undef COMPUTE

  // Epilogue: verified 32x32 C/D layout: col = lane&31,
  // row = (reg&3) + 8*(reg>>2) + 4*(lane>>5).
  const float scale = -0.5f * 0.04419417382415922f;
  const int col = bn + wc * 32 + (lane & 31);
#pragma unroll
  for (int f = 0; f < 2; ++f) {
#pragma unroll
    for (int reg = 0; reg < 16; ++reg) {
      const int row = bm + wr * 64 + f * 32 + (reg & 3) + 8 * (reg >> 2)
                    + 4 * (lane >> 5);
      out[(size_t)row * D_ROWS + col] = acc[f][reg] * scale;
    }
  }
}

extern "C" void kernel_launch(void* const* d_in, const int* in_sizes, int n_in,
                              void* d_out, int out_size, void* d_ws, size_t ws_size,
                              hipStream_t stream) {
  const int*   x = (const int*)d_in[0];     // (4096, 2048) int32
  const float* r = (const float*)d_in[1];   // (1024, 2048) float32
  float*     out = (float*)d_out;           // (4096, 1024) float32

  uint8_t* Aq = (uint8_t*)d_ws;                         // 4 MiB (4096x1024 B)
  uint8_t* Bq = Aq + (size_t)B_ROWS * LB;               // 1 MiB (1024x1024 B)

  convert_fp4_kernel<<<CVT_BLOCKS, 256, 0, stream>>>(
      x, r, (uint32_t*)Aq, (uint32_t*)Bq);

  gemm_fp4_kernel<<<NWG, 256, 0, stream>>>(Aq, Bq, out);  // 512 blocks
}